// Round 1
// baseline (192.149 us; speedup 1.0000x reference)
//
#include <hip/hip_runtime.h>
#include <hip/hip_bf16.h>

typedef short short8 __attribute__((ext_vector_type(8)));
typedef float f32x4 __attribute__((ext_vector_type(4)));

#define LDS_BYTES 163840
// LDS layout (byte offsets). Lifetimes:
//  XS  [0,64K)      x row bf16 [c][w], alive whole kernel (Y-GEMM A operand)
//  XN  [64K,128K)   xn^T bf16 [w][c], alive LN->S
//  AT  [64K,96K)    attention A bf16 [w][v], written after S (xn dead)
//  YT  [96K,160K)   Y^T bf16 [w][c], written after S/softmax
//  GB  [128K,136K)  G band bf16 [v][o'] (32 cols), alive only inside S loop
//  misc scratch at 136K+, all dead before YT is written
#define XS 0
#define XN 65536
#define AT 65536
#define YT 98304
#define GB 131072
#define SUMSO 139264
#define SQSO 141312
#define MUO 143360
#define RSO 143872
#define UDO 144384

__device__ inline unsigned short cvtbf(float f){
  unsigned int x = __float_as_uint(f);
  x += 0x7fffu + ((x >> 16) & 1u);           // RNE
  return (unsigned short)(x >> 16);
}
__device__ inline float bf2f(unsigned short u){ return __uint_as_float(((unsigned int)u) << 16); }
__device__ inline unsigned int pk2(float a, float b){ return (unsigned int)cvtbf(a) | ((unsigned int)cvtbf(b) << 16); }

// setup: M = wq^T wk (bf16), wv -> bf16, u = wk^T bq
__global__ void __launch_bounds__(256) setup_kernel(
    const float* __restrict__ wq, const float* __restrict__ bq,
    const float* __restrict__ wk, const float* __restrict__ wvw,
    unsigned short* __restrict__ Mbf, unsigned short* __restrict__ wvbf, float* __restrict__ u){
  int c1 = blockIdx.x, t = threadIdx.x;
  float acc = 0.f;
  for (int o = 0; o < 256; ++o) acc = fmaf(wq[o*256 + c1], wk[o*256 + t], acc);
  Mbf[c1*256 + t] = cvtbf(acc);
  wvbf[c1*256 + t] = cvtbf(wvw[c1*256 + t]);
  if (c1 == 0){
    float a2 = 0.f;
    for (int o = 0; o < 256; ++o) a2 = fmaf(wk[o*256 + t], bq[o], a2);
    u[t] = a2;
  }
}

__global__ void __launch_bounds__(512, 2) fused_kernel(
    const float* __restrict__ x, const float* __restrict__ nw, const float* __restrict__ nb,
    const float* __restrict__ bvv, const float* __restrict__ beta,
    const unsigned short* __restrict__ Mbf, const unsigned short* __restrict__ wvbf,
    const float* __restrict__ u, float* __restrict__ out){
  extern __shared__ char smem[];
  const int t = threadIdx.x;
  const int lane = t & 63, wv8 = t >> 6;      // 8 waves
  const int g = lane >> 4, li = lane & 15;
  const int blk = blockIdx.x;
  const int b = blk >> 7, h = blk & 127;
  const size_t base = (size_t)b*4194304 + (size_t)h*128;  // x[b,c,h,w] = base + c*16384 + w

  // ---- P0: load x row -> x_s bf16 [c][w], row-swizzled
  #pragma unroll
  for (int i = 0; i < 16; ++i){
    int f = t + i*512;
    int c = f >> 5, w4 = f & 31;
    const float4 v = *(const float4*)(x + base + (size_t)c*16384 + (size_t)(w4*4));
    uint2 p; p.x = pk2(v.x, v.y); p.y = pk2(v.z, v.w);
    *(uint2*)(smem + XS + c*256 + ((w4*8) ^ ((c&7)<<4))) = p;
  }
  __syncthreads();

  // ---- P1: LN stats per w (mean/var over c)
  {
    int w = t & 127, s = t >> 7;
    float sm = 0.f, sq = 0.f;
    for (int j = 0; j < 64; ++j){
      int c = s*64 + j;
      float xv = bf2f(*(const unsigned short*)(smem + XS + c*256 + ((2*w) ^ ((c&7)<<4))));
      sm += xv; sq += xv*xv;
    }
    ((float*)(smem + SUMSO))[s*128 + w] = sm;
    ((float*)(smem + SQSO))[s*128 + w] = sq;
  }
  __syncthreads();
  if (t < 128){
    float sm = 0.f, sq = 0.f;
    for (int s = 0; s < 4; ++s){ sm += ((float*)(smem+SUMSO))[s*128+t]; sq += ((float*)(smem+SQSO))[s*128+t]; }
    float mu = sm * (1.f/256.f);
    float var = sq * (1.f/256.f) - mu*mu;
    ((float*)(smem+MUO))[t] = mu;
    ((float*)(smem+RSO))[t] = rsqrtf(var + 1e-6f);
  }
  __syncthreads();

  // ---- P2: xn^T [w][c] = normalize+transpose; udot partials
  {
    int w = t & 127, s = t >> 7;
    float mu = ((float*)(smem+MUO))[w], rs = ((float*)(smem+RSO))[w];
    float ud = 0.f;
    for (int i = 0; i < 8; ++i){
      int c0 = s*64 + i*8;
      short8 o8;
      #pragma unroll
      for (int j = 0; j < 8; ++j){
        int c = c0 + j;
        float xv = bf2f(*(const unsigned short*)(smem + XS + c*256 + ((2*w) ^ ((c&7)<<4))));
        float xnv = (xv - mu)*rs*nw[c] + nb[c];
        o8[j] = (short)cvtbf(xnv);
        ud = fmaf(u[c], xnv, ud);
      }
      *(short8*)(smem + XN + w*512 + ((2*c0) ^ ((w&7)<<4))) = o8;
    }
    ((float*)(smem+SUMSO))[s*128 + w] = ud;
  }
  __syncthreads();
  if (t < 128){
    float ud = 0.f; for (int s = 0; s < 4; ++s) ud += ((float*)(smem+SUMSO))[s*128+t];
    ((float*)(smem+UDO))[t] = ud;
  }
  __syncthreads();

  // ---- P3: S^T[v][w] = sum_o G[o][v]*xn[o][w] (+udot[v]), G in 32-row bands
  f32x4 Sacc[8];
  #pragma unroll
  for (int vt = 0; vt < 8; ++vt){
    int vb = vt*16 + g*4;
    #pragma unroll
    for (int r = 0; r < 4; ++r) Sacc[vt][r] = ((float*)(smem+UDO))[vb + r];
  }
  const int ot = wv8 >> 2, vp = wv8 & 3;
  const int wt = wv8;
  for (int k8 = 0; k8 < 8; ++k8){
    // G band: Gband[o'][v], o' in [0,32): this wave does 16 o' x 32 v
    f32x4 Ga[2] = {{0.f,0.f,0.f,0.f},{0.f,0.f,0.f,0.f}};
    #pragma unroll
    for (int kk = 0; kk < 8; ++kk){
      int o = k8*32 + ot*16 + li;
      short8 afr = *(const short8*)(Mbf + o*256 + kk*32 + g*8);
      #pragma unroll
      for (int j = 0; j < 2; ++j){
        int v = (vp*2 + j)*16 + li;
        short8 bfr = *(const short8*)(smem + XN + v*512 + ((2*(kk*32 + g*8)) ^ ((v&7)<<4)));
        Ga[j] = __builtin_amdgcn_mfma_f32_16x16x32_bf16(afr, bfr, Ga[j], 0, 0, 0);
      }
    }
    __syncthreads();  // prev chunk's S reads of GB complete
    #pragma unroll
    for (int j = 0; j < 2; ++j){
      int v = (vp*2 + j)*16 + li;
      int ob = ot*16 + g*4;
      uint2 p; p.x = pk2(Ga[j][0], Ga[j][1]); p.y = pk2(Ga[j][2], Ga[j][3]);
      *(uint2*)(smem + GB + v*64 + ((2*ob) ^ ((v&3)<<4))) = p;
    }
    __syncthreads();
    // S accumulation: this wave owns w-tile wt (all v)
    {
      int w = wt*16 + li;
      short8 bfr = *(const short8*)(smem + XN + w*512 + ((2*(k8*32 + g*8)) ^ ((w&7)<<4)));
      #pragma unroll
      for (int vt = 0; vt < 8; ++vt){
        int v = vt*16 + li;
        short8 afr = *(const short8*)(smem + GB + v*64 + ((16*g) ^ ((v&3)<<4)));
        Sacc[vt] = __builtin_amdgcn_mfma_f32_16x16x32_bf16(afr, bfr, Sacc[vt], 0, 0, 0);
      }
    }
  }
  __syncthreads();

  // ---- softmax over v (rows of S^T): in-lane 32 vals + xor16/32
  float mx = -3.4e38f;
  #pragma unroll
  for (int vt = 0; vt < 8; ++vt)
    #pragma unroll
    for (int r = 0; r < 4; ++r){ float sv = Sacc[vt][r]*0.0625f; Sacc[vt][r] = sv; mx = fmaxf(mx, sv); }
  mx = fmaxf(mx, __shfl_xor(mx, 16));
  mx = fmaxf(mx, __shfl_xor(mx, 32));
  float sum = 0.f;
  #pragma unroll
  for (int vt = 0; vt < 8; ++vt)
    #pragma unroll
    for (int r = 0; r < 4; ++r){ float p = exp2f((Sacc[vt][r]-mx)*1.44269504f); Sacc[vt][r] = p; sum += p; }
  sum += __shfl_xor(sum, 16);
  sum += __shfl_xor(sum, 32);
  float inv = 1.f / sum;
  {
    int w = wt*16 + li;
    #pragma unroll
    for (int vt = 0; vt < 8; ++vt){
      uint2 p; p.x = pk2(Sacc[vt][0]*inv, Sacc[vt][1]*inv); p.y = pk2(Sacc[vt][2]*inv, Sacc[vt][3]*inv);
      int vb = vt*16 + g*4;
      *(uint2*)(smem + AT + w*256 + ((2*vb) ^ ((w&7)<<4))) = p;
    }
  }
  __syncthreads();

  // ---- P4: Y[c][w] = sum_v x[c][v] * A[w][v]
  f32x4 Yacc[2][8];
  #pragma unroll
  for (int ci = 0; ci < 2; ++ci)
    #pragma unroll
    for (int w2 = 0; w2 < 8; ++w2) Yacc[ci][w2] = (f32x4){0.f,0.f,0.f,0.f};
  #pragma unroll
  for (int kk = 0; kk < 4; ++kk){
    short8 afr[2];
    #pragma unroll
    for (int ci = 0; ci < 2; ++ci){
      int c = (wv8*2 + ci)*16 + li;
      afr[ci] = *(const short8*)(smem + XS + c*256 + ((2*(kk*32 + g*8)) ^ ((c&7)<<4)));
    }
    #pragma unroll
    for (int w2 = 0; w2 < 8; ++w2){
      int w = w2*16 + li;
      short8 bfr = *(const short8*)(smem + AT + w*256 + ((2*(kk*32 + g*8)) ^ ((w&7)<<4)));
      #pragma unroll
      for (int ci = 0; ci < 2; ++ci)
        Yacc[ci][w2] = __builtin_amdgcn_mfma_f32_16x16x32_bf16(afr[ci], bfr, Yacc[ci][w2], 0, 0, 0);
    }
  }
  // write Y^T [w][c]
  #pragma unroll
  for (int ci = 0; ci < 2; ++ci){
    int cb = (wv8*2 + ci)*16 + g*4;
    #pragma unroll
    for (int w2 = 0; w2 < 8; ++w2){
      int w = w2*16 + li;
      uint2 p; p.x = pk2(Yacc[ci][w2][0], Yacc[ci][w2][1]); p.y = pk2(Yacc[ci][w2][2], Yacc[ci][w2][3]);
      *(uint2*)(smem + YT + w*512 + ((2*cb) ^ ((w&7)<<4))) = p;
    }
  }
  __syncthreads();

  // ---- P5: F[o][w] = sum_c wv[o][c] Y[c][w]; out = x + (F+bv)*beta
  f32x4 Facc[2][8];
  #pragma unroll
  for (int oi = 0; oi < 2; ++oi)
    #pragma unroll
    for (int w2 = 0; w2 < 8; ++w2) Facc[oi][w2] = (f32x4){0.f,0.f,0.f,0.f};
  #pragma unroll
  for (int kk = 0; kk < 8; ++kk){
    short8 afr[2];
    #pragma unroll
    for (int oi = 0; oi < 2; ++oi){
      int o = (wv8*2 + oi)*16 + li;
      afr[oi] = *(const short8*)(wvbf + o*256 + kk*32 + g*8);
    }
    #pragma unroll
    for (int w2 = 0; w2 < 8; ++w2){
      int w = w2*16 + li;
      short8 bfr = *(const short8*)(smem + YT + w*512 + ((2*(kk*32 + g*8)) ^ ((w&7)<<4)));
      #pragma unroll
      for (int oi = 0; oi < 2; ++oi)
        Facc[oi][w2] = __builtin_amdgcn_mfma_f32_16x16x32_bf16(afr[oi], bfr, Facc[oi][w2], 0, 0, 0);
    }
  }
  #pragma unroll
  for (int oi = 0; oi < 2; ++oi){
    #pragma unroll
    for (int r = 0; r < 4; ++r){
      int o = (wv8*2 + oi)*16 + g*4 + r;
      float bvo = bvv[o], bto = beta[o];
      #pragma unroll
      for (int w2 = 0; w2 < 8; ++w2){
        int w = w2*16 + li;
        size_t idx = base + (size_t)o*16384 + (size_t)w;
        out[idx] = x[idx] + (Facc[oi][w2][r] + bvo)*bto;
      }
    }
  }
}

extern "C" void kernel_launch(void* const* d_in, const int* in_sizes, int n_in,
                              void* d_out, int out_size, void* d_ws, size_t ws_size,
                              hipStream_t stream) {
  (void)in_sizes; (void)n_in; (void)out_size; (void)ws_size;
  const float* x      = (const float*)d_in[0];
  const float* norm_w = (const float*)d_in[1];
  const float* norm_b = (const float*)d_in[2];
  const float* wq     = (const float*)d_in[3];
  const float* bq     = (const float*)d_in[4];
  const float* wk     = (const float*)d_in[5];
  // d_in[6] = bk: only enters softmax-invariant terms, mathematically dropped
  const float* wvw    = (const float*)d_in[7];
  const float* bvv    = (const float*)d_in[8];
  const float* beta   = (const float*)d_in[9];
  float* out = (float*)d_out;

  unsigned short* Mbf  = (unsigned short*)d_ws;                    // 128 KB
  unsigned short* wvbf = (unsigned short*)((char*)d_ws + 131072);  // 128 KB
  float* u             = (float*)((char*)d_ws + 262144);           // 1 KB

  static bool attr_set = false;
  if (!attr_set) {
    (void)hipFuncSetAttribute((const void*)fused_kernel,
                              hipFuncAttributeMaxDynamicSharedMemorySize, LDS_BYTES);
    attr_set = true;
  }

  setup_kernel<<<256, 256, 0, stream>>>(wq, bq, wk, wvw, Mbf, wvbf, u);
  fused_kernel<<<1024, 512, LDS_BYTES, stream>>>(x, norm_w, norm_b, bvv, beta, Mbf, wvbf, u, out);
}